// Round 4
// baseline (193.822 us; speedup 1.0000x reference)
//
#include <hip/hip_runtime.h>
#include <math.h>

#define NF 1000
#define NC 1000
#define NB 16384
#define NV 250          // NF/4 float4s per row
#define ALPHA_C 0.5f
#define BETA_C 0.003f
#define GAMMA_C 0.001f

__device__ __forceinline__ float wave_sum(float v) {
#pragma unroll
    for (int off = 32; off > 0; off >>= 1) v += __shfl_xor(v, off, 64);
    return v;
}
__device__ __forceinline__ float wave_max(float v) {
#pragma unroll
    for (int off = 32; off > 0; off >>= 1) v = fmaxf(v, __shfl_xor(v, off, 64));
    return v;
}

// One wave per row (4 rows per 256-thread block). All 9 loads issued up front
// so HBM latency overlaps the reductions.
__global__ __launch_bounds__(256) void row_pass(
    const float* __restrict__ x, const int* __restrict__ y,
    const float* __restrict__ centers,
    float* __restrict__ ce, float* __restrict__ d2, int* __restrict__ counts) {
    const int wid = threadIdx.x >> 6, lane = threadIdx.x & 63;
    const int b = blockIdx.x * 4 + wid;
    const int cls = y[b];
    const float4* xrow = (const float4*)(x + (size_t)b * NF);
    const float4* crow = (const float4*)(centers + (size_t)cls * NF);

    float4 xv[4], cv[4];
#pragma unroll
    for (int i = 0; i < 4; i++) {
        int idx = lane + i * 64;
        if (idx < NV) {
            xv[i] = xrow[idx];
            cv[i] = crow[idx];
        } else {
            xv[i] = make_float4(-INFINITY, -INFINITY, -INFINITY, -INFINITY);
            cv[i] = make_float4(0.f, 0.f, 0.f, 0.f);
        }
    }
    const float xy = x[(size_t)b * NF + cls];   // x[b, y[b]] (C == F)

    float lmax = -INFINITY;
#pragma unroll
    for (int i = 0; i < 4; i++)
        lmax = fmaxf(fmaxf(fmaxf(lmax, xv[i].x), fmaxf(xv[i].y, xv[i].z)), xv[i].w);
    const float rmax = wave_max(lmax);

    float lsum = 0.f, ld2 = 0.f;
#pragma unroll
    for (int i = 0; i < 4; i++) {
        int idx = lane + i * 64;
        // expf(-INF - rmax) == 0, so inactive slots contribute nothing
        lsum += expf(xv[i].x - rmax) + expf(xv[i].y - rmax) +
                expf(xv[i].z - rmax) + expf(xv[i].w - rmax);
        if (idx < NV) {
            float dx = xv[i].x - cv[i].x, dy = xv[i].y - cv[i].y;
            float dz = xv[i].z - cv[i].z, dw = xv[i].w - cv[i].w;
            ld2 += dx * dx + dy * dy + dz * dz + dw * dw;
        }
    }
    const float sumexp = wave_sum(lsum);
    const float rd2 = wave_sum(ld2);
    if (lane == 0) {
        ce[b] = -(xy - rmax - logf(sumexp));
        d2[b] = rd2;
        atomicAdd(&counts[cls], 1);
    }
}

// Single block: Hillis-Steele scan of counts -> offsets, then scatter row ids
// via LDS cursors (order within a class is irrelevant).
__global__ __launch_bounds__(1024) void scan_scatter(
    const int* __restrict__ counts, const int* __restrict__ y,
    int* __restrict__ offsets, int* __restrict__ rids) {
    __shared__ int s[1024];
    __shared__ int cur[1024];
    const int t = threadIdx.x;
    const int v = (t < NC) ? counts[t] : 0;
    s[t] = v;
    __syncthreads();
    for (int d = 1; d < 1024; d <<= 1) {
        int add = (t >= d) ? s[t - d] : 0;
        __syncthreads();
        s[t] += add;
        __syncthreads();
    }
    const int excl = s[t] - v;
    if (t < NC) offsets[t] = excl;
    cur[t] = excl;
    __syncthreads();
    for (int b = t; b < NB; b += 1024) {
        int cls = y[b];
        int p = atomicAdd(&cur[cls], 1);
        rids[p] = b;
    }
}

// One block per class. Row ids staged in LDS (one coalesced read), row loop
// unrolled 4-deep with independent accumulators for memory-level parallelism.
__global__ __launch_bounds__(256) void class_pass(
    const float* __restrict__ x, const float* __restrict__ centers,
    const int* __restrict__ counts, const int* __restrict__ offsets,
    const int* __restrict__ rids,
    const float* __restrict__ ce, const float* __restrict__ d2,
    float* __restrict__ new_centers, float* __restrict__ scalars) {
    __shared__ float sb[16];
    __shared__ int s_rid[64];
    const int c = blockIdx.x, t = threadIdx.x;
    const int n = counts[c], off = offsets[c];

    float4 a0 = make_float4(0, 0, 0, 0), a1 = make_float4(0, 0, 0, 0);
    float4 a2 = make_float4(0, 0, 0, 0), a3 = make_float4(0, 0, 0, 0);
    float lce = 0.f, ld2 = 0.f;

    for (int base = 0; base < n; base += 64) {
        const int m = min(64, n - base);
        __syncthreads();                 // protect s_rid reuse across chunks
        if (t < m) {
            int b = rids[off + base + t];
            s_rid[t] = b;
            lce += ce[b];
            ld2 += d2[b];
        }
        __syncthreads();
        if (t < NV) {
            int i = 0;
            for (; i + 3 < m; i += 4) {
                const float4 v0 = ((const float4*)(x + (size_t)s_rid[i + 0] * NF))[t];
                const float4 v1 = ((const float4*)(x + (size_t)s_rid[i + 1] * NF))[t];
                const float4 v2 = ((const float4*)(x + (size_t)s_rid[i + 2] * NF))[t];
                const float4 v3 = ((const float4*)(x + (size_t)s_rid[i + 3] * NF))[t];
                a0.x += v0.x; a0.y += v0.y; a0.z += v0.z; a0.w += v0.w;
                a1.x += v1.x; a1.y += v1.y; a1.z += v1.z; a1.w += v1.w;
                a2.x += v2.x; a2.y += v2.y; a2.z += v2.z; a2.w += v2.w;
                a3.x += v3.x; a3.y += v3.y; a3.z += v3.z; a3.w += v3.w;
            }
            for (; i < m; i++) {
                const float4 v0 = ((const float4*)(x + (size_t)s_rid[i] * NF))[t];
                a0.x += v0.x; a0.y += v0.y; a0.z += v0.z; a0.w += v0.w;
            }
        }
    }
    a0.x += a1.x + a2.x + a3.x; a0.y += a1.y + a2.y + a3.y;
    a0.z += a1.z + a2.z + a3.z; a0.w += a1.w + a2.w + a3.w;

    const float inv = (n > 0) ? 1.f / (float)n : 0.f;
    float lsq = 0.f, lmd2 = 0.f;
    if (t < NV) {
        float4 cv = ((const float4*)(centers + (size_t)c * NF))[t];
        float4 md, nc;
        md.x = (n > 0) ? (a0.x * inv - cv.x) : 0.f;
        md.y = (n > 0) ? (a0.y * inv - cv.y) : 0.f;
        md.z = (n > 0) ? (a0.z * inv - cv.z) : 0.f;
        md.w = (n > 0) ? (a0.w * inv - cv.w) : 0.f;
        nc.x = cv.x + ALPHA_C * md.x; nc.y = cv.y + ALPHA_C * md.y;
        nc.z = cv.z + ALPHA_C * md.z; nc.w = cv.w + ALPHA_C * md.w;
        ((float4*)(new_centers + (size_t)c * NF))[t] = nc;
        lsq = nc.x * nc.x + nc.y * nc.y + nc.z * nc.z + nc.w * nc.w;
        lmd2 = md.x * md.x + md.y * md.y + md.z * md.z + md.w * md.w;
    }

    float w0 = wave_sum(lsq), w1 = wave_sum(lmd2), w2 = wave_sum(lce), w3 = wave_sum(ld2);
    const int wid = t >> 6, lane = t & 63;
    if (lane == 0) { sb[wid] = w0; sb[4 + wid] = w1; sb[8 + wid] = w2; sb[12 + wid] = w3; }
    __syncthreads();
    if (t == 0) {
        float sq  = sb[0] + sb[1] + sb[2] + sb[3];
        float md2 = sb[4] + sb[5] + sb[6] + sb[7];
        float ces = sb[8] + sb[9] + sb[10] + sb[11];
        float s2  = sb[12] + sb[13] + sb[14] + sb[15];
        atomicAdd(&scalars[0], ces);
        atomicAdd(&scalars[1], s2);
        atomicAdd(&scalars[2], sq);
        // per-class intra mean: S2/n - alpha*(2-alpha)*||md||^2
        float intra = (n > 0) ? (s2 * inv - ALPHA_C * (2.f - ALPHA_C) * md2) : 0.f;
        atomicAdd(&scalars[3], intra);
    }
}

// Partial column sums: grid (4, 16); blockIdx.y strides classes.
__global__ __launch_bounds__(256) void col_partial(
    const float* __restrict__ new_centers, float* __restrict__ s) {
    const int f = blockIdx.x * 256 + threadIdx.x;
    if (f >= NF) return;
    float acc = 0.f;
    for (int c = blockIdx.y; c < NC; c += gridDim.y)
        acc += new_centers[(size_t)c * NF + f];
    atomicAdd(&s[f], acc);
}

__global__ __launch_bounds__(1024) void finalize(
    const float* __restrict__ s, const float* __restrict__ scalars,
    float* __restrict__ out) {
    __shared__ float sb[16];
    const int t = threadIdx.x;
    float v = (t < NF) ? s[t] * s[t] : 0.f;
    float w = wave_sum(v);
    if ((t & 63) == 0) sb[t >> 6] = w;
    __syncthreads();
    if (t == 0) {
        float ssq = 0.f;
        for (int k = 0; k < 16; k++) ssq += sb[k];
        float cem = scalars[0] / (float)NB;
        float cl = scalars[1] / (float)NB;
        float num_pairs = (float)NC * (float)(NC - 1) * 0.5f;
        float inter = ((float)NC * scalars[2] - ssq) / num_pairs;
        float intra = scalars[3] / (float)NC;
        out[0] = cem + BETA_C * cl + GAMMA_C * inter + GAMMA_C * intra;
    }
}

extern "C" void kernel_launch(void* const* d_in, const int* in_sizes, int n_in,
                              void* d_out, int out_size, void* d_ws, size_t ws_size,
                              hipStream_t stream) {
    const float* x = (const float*)d_in[0];
    const int* y = (const int*)d_in[1];
    const float* centers = (const float*)d_in[2];
    float* out = (float*)d_out;

    char* ws = (char*)d_ws;
    float* ce      = (float*)(ws);                    // 65536 B
    float* d2      = (float*)(ws + 65536);            // 65536 B
    int* rids      = (int*)(ws + 131072);             // 65536 B
    int* offsets   = (int*)(ws + 196608);             // 4096 B
    // --- zeroed region (one memset) ---
    int* counts    = (int*)(ws + 200704);             // 4096 B
    float* s       = (float*)(ws + 204800);           // 4096 B
    float* scalars = (float*)(ws + 208896);           // 64 B
    // --- end zeroed region (8256 B) ---
    float* new_centers = (float*)(ws + 208960);       // 4,000,000 B

    hipMemsetAsync(counts, 0, 8256, stream);

    row_pass<<<NB / 4, 256, 0, stream>>>(x, y, centers, ce, d2, counts);
    scan_scatter<<<1, 1024, 0, stream>>>(counts, y, offsets, rids);
    class_pass<<<NC, 256, 0, stream>>>(x, centers, counts, offsets, rids,
                                       ce, d2, new_centers, scalars);
    dim3 cgrid(4, 16);
    col_partial<<<cgrid, 256, 0, stream>>>(new_centers, s);
    finalize<<<1, 1024, 0, stream>>>(s, scalars, out);
}

// Round 5
// 138.216 us; speedup vs baseline: 1.4023x; 1.4023x over previous
//
#include <hip/hip_runtime.h>
#include <math.h>

#define NF 1000
#define NC 1000
#define NB 16384
#define NV 250          // NF/4 float4s per row
#define ALPHA_C 0.5f
#define BETA_C 0.003f
#define GAMMA_C 0.001f
#define MAXL 512        // LDS row-list capacity (multinomial max ~40; huge margin)

__device__ __forceinline__ float wave_sum(float v) {
#pragma unroll
    for (int off = 32; off > 0; off >>= 1) v += __shfl_xor(v, off, 64);
    return v;
}
__device__ __forceinline__ float wave_max(float v) {
#pragma unroll
    for (int off = 32; off > 0; off >>= 1) v = fmaxf(v, __shfl_xor(v, off, 64));
    return v;
}

// One wave per row (4 rows per 256-thread block). All loads issued up front.
// No atomics.
__global__ __launch_bounds__(256) void row_pass(
    const float* __restrict__ x, const int* __restrict__ y,
    const float* __restrict__ centers,
    float* __restrict__ ce, float* __restrict__ d2) {
    const int wid = threadIdx.x >> 6, lane = threadIdx.x & 63;
    const int b = blockIdx.x * 4 + wid;
    const int cls = y[b];
    const float4* xrow = (const float4*)(x + (size_t)b * NF);
    const float4* crow = (const float4*)(centers + (size_t)cls * NF);

    float4 xv[4], cv[4];
#pragma unroll
    for (int i = 0; i < 4; i++) {
        int idx = lane + i * 64;
        if (idx < NV) {
            xv[i] = xrow[idx];
            cv[i] = crow[idx];
        } else {
            xv[i] = make_float4(-INFINITY, -INFINITY, -INFINITY, -INFINITY);
            cv[i] = make_float4(0.f, 0.f, 0.f, 0.f);
        }
    }
    const float xy = x[(size_t)b * NF + cls];   // x[b, y[b]] (C == F)

    float lmax = -INFINITY;
#pragma unroll
    for (int i = 0; i < 4; i++)
        lmax = fmaxf(fmaxf(fmaxf(lmax, xv[i].x), fmaxf(xv[i].y, xv[i].z)), xv[i].w);
    const float rmax = wave_max(lmax);

    float lsum = 0.f, ld2 = 0.f;
#pragma unroll
    for (int i = 0; i < 4; i++) {
        int idx = lane + i * 64;
        // expf(-INF - rmax) == 0: inactive slots contribute nothing
        lsum += expf(xv[i].x - rmax) + expf(xv[i].y - rmax) +
                expf(xv[i].z - rmax) + expf(xv[i].w - rmax);
        if (idx < NV) {
            float dx = xv[i].x - cv[i].x, dy = xv[i].y - cv[i].y;
            float dz = xv[i].z - cv[i].z, dw = xv[i].w - cv[i].w;
            ld2 += dx * dx + dy * dy + dz * dz + dw * dw;
        }
    }
    const float sumexp = wave_sum(lsum);
    const float rd2 = wave_sum(ld2);
    if (lane == 0) {
        ce[b] = -(xy - rmax - logf(sumexp));
        d2[b] = rd2;
    }
}

// One block per class. Scans y directly (L2-resident) to build its row list
// in LDS -- no global sort/scan/scatter needed. Then gathers x rows with
// 4-deep independent accumulators. Epilogue writes per-class partials
// (NO contended atomics).
__global__ __launch_bounds__(256) void class_pass(
    const float* __restrict__ x, const int* __restrict__ y,
    const float* __restrict__ centers,
    const float* __restrict__ ce, const float* __restrict__ d2,
    float* __restrict__ new_centers, float4* __restrict__ partials) {
    __shared__ float sb[16];
    __shared__ int list[MAXL];
    __shared__ int lcount;
    const int c = blockIdx.x, t = threadIdx.x;
    if (t == 0) lcount = 0;
    __syncthreads();

    const int4* y4 = (const int4*)y;
    for (int i = t; i < NB / 4; i += 256) {
        int4 v = y4[i];
        int b = 4 * i;
        if (v.x == c) { int p = atomicAdd(&lcount, 1); list[p & (MAXL - 1)] = b; }
        if (v.y == c) { int p = atomicAdd(&lcount, 1); list[p & (MAXL - 1)] = b + 1; }
        if (v.z == c) { int p = atomicAdd(&lcount, 1); list[p & (MAXL - 1)] = b + 2; }
        if (v.w == c) { int p = atomicAdd(&lcount, 1); list[p & (MAXL - 1)] = b + 3; }
    }
    __syncthreads();
    const int n = lcount;

    float lce = 0.f, ld2 = 0.f;
    for (int j = t; j < n; j += 256) {
        int b = list[j];
        lce += ce[b];
        ld2 += d2[b];
    }

    float4 a0 = make_float4(0, 0, 0, 0), a1 = make_float4(0, 0, 0, 0);
    float4 a2 = make_float4(0, 0, 0, 0), a3 = make_float4(0, 0, 0, 0);
    if (t < NV) {
        int i = 0;
        for (; i + 3 < n; i += 4) {
            const float4 v0 = ((const float4*)(x + (size_t)list[i + 0] * NF))[t];
            const float4 v1 = ((const float4*)(x + (size_t)list[i + 1] * NF))[t];
            const float4 v2 = ((const float4*)(x + (size_t)list[i + 2] * NF))[t];
            const float4 v3 = ((const float4*)(x + (size_t)list[i + 3] * NF))[t];
            a0.x += v0.x; a0.y += v0.y; a0.z += v0.z; a0.w += v0.w;
            a1.x += v1.x; a1.y += v1.y; a1.z += v1.z; a1.w += v1.w;
            a2.x += v2.x; a2.y += v2.y; a2.z += v2.z; a2.w += v2.w;
            a3.x += v3.x; a3.y += v3.y; a3.z += v3.z; a3.w += v3.w;
        }
        for (; i < n; i++) {
            const float4 v0 = ((const float4*)(x + (size_t)list[i] * NF))[t];
            a0.x += v0.x; a0.y += v0.y; a0.z += v0.z; a0.w += v0.w;
        }
    }
    a0.x += a1.x + a2.x + a3.x; a0.y += a1.y + a2.y + a3.y;
    a0.z += a1.z + a2.z + a3.z; a0.w += a1.w + a2.w + a3.w;

    const float inv = (n > 0) ? 1.f / (float)n : 0.f;
    float lsq = 0.f, lmd2 = 0.f;
    if (t < NV) {
        float4 cv = ((const float4*)(centers + (size_t)c * NF))[t];
        float4 md, nc;
        md.x = (n > 0) ? (a0.x * inv - cv.x) : 0.f;
        md.y = (n > 0) ? (a0.y * inv - cv.y) : 0.f;
        md.z = (n > 0) ? (a0.z * inv - cv.z) : 0.f;
        md.w = (n > 0) ? (a0.w * inv - cv.w) : 0.f;
        nc.x = cv.x + ALPHA_C * md.x; nc.y = cv.y + ALPHA_C * md.y;
        nc.z = cv.z + ALPHA_C * md.z; nc.w = cv.w + ALPHA_C * md.w;
        ((float4*)(new_centers + (size_t)c * NF))[t] = nc;
        lsq = nc.x * nc.x + nc.y * nc.y + nc.z * nc.z + nc.w * nc.w;
        lmd2 = md.x * md.x + md.y * md.y + md.z * md.z + md.w * md.w;
    }

    float w0 = wave_sum(lsq), w1 = wave_sum(lmd2), w2 = wave_sum(lce), w3 = wave_sum(ld2);
    const int wid = t >> 6, lane = t & 63;
    if (lane == 0) { sb[wid] = w0; sb[4 + wid] = w1; sb[8 + wid] = w2; sb[12 + wid] = w3; }
    __syncthreads();
    if (t == 0) {
        float sq  = sb[0] + sb[1] + sb[2] + sb[3];
        float md2 = sb[4] + sb[5] + sb[6] + sb[7];
        float ces = sb[8] + sb[9] + sb[10] + sb[11];
        float s2  = sb[12] + sb[13] + sb[14] + sb[15];
        // per-class intra mean: S2/n - alpha*(2-alpha)*||md||^2
        float intra = (n > 0) ? (s2 * inv - ALPHA_C * (2.f - ALPHA_C) * md2) : 0.f;
        partials[c] = make_float4(ces, s2, sq, intra);
    }
}

// Partial column sums, no atomics: block (bx,by) writes s_part[by*NF + f].
__global__ __launch_bounds__(256) void col_partial(
    const float* __restrict__ new_centers, float* __restrict__ s_part) {
    const int f = blockIdx.x * 256 + threadIdx.x;
    if (f >= NF) return;
    float acc = 0.f;
    for (int c = blockIdx.y; c < NC; c += gridDim.y)
        acc += new_centers[(size_t)c * NF + f];
    s_part[blockIdx.y * NF + f] = acc;
}

__global__ __launch_bounds__(1024) void finalize(
    const float* __restrict__ s_part, const float4* __restrict__ partials,
    float* __restrict__ out) {
    __shared__ float sb[80];
    const int t = threadIdx.x;
    float ssq = 0.f, ces = 0.f, s2 = 0.f, sq = 0.f, intra = 0.f;
    if (t < NC) {
        float s = 0.f;
#pragma unroll
        for (int k = 0; k < 16; k++) s += s_part[k * NF + t];
        ssq = s * s;
        float4 p = partials[t];
        ces = p.x; s2 = p.y; sq = p.z; intra = p.w;
    }
    float w0 = wave_sum(ssq), w1 = wave_sum(ces), w2 = wave_sum(s2);
    float w3 = wave_sum(sq), w4 = wave_sum(intra);
    const int wid = t >> 6, lane = t & 63;
    if (lane == 0) {
        sb[wid] = w0; sb[16 + wid] = w1; sb[32 + wid] = w2;
        sb[48 + wid] = w3; sb[64 + wid] = w4;
    }
    __syncthreads();
    if (t == 0) {
        float Sssq = 0.f, Sces = 0.f, Ss2 = 0.f, Ssq = 0.f, Sintra = 0.f;
        for (int k = 0; k < 16; k++) {
            Sssq += sb[k]; Sces += sb[16 + k]; Ss2 += sb[32 + k];
            Ssq += sb[48 + k]; Sintra += sb[64 + k];
        }
        float cem = Sces / (float)NB;
        float cl = Ss2 / (float)NB;
        float num_pairs = (float)NC * (float)(NC - 1) * 0.5f;
        float inter = ((float)NC * Ssq - Sssq) / num_pairs;
        float intra_l = Sintra / (float)NC;
        out[0] = cem + BETA_C * cl + GAMMA_C * inter + GAMMA_C * intra_l;
    }
}

extern "C" void kernel_launch(void* const* d_in, const int* in_sizes, int n_in,
                              void* d_out, int out_size, void* d_ws, size_t ws_size,
                              hipStream_t stream) {
    const float* x = (const float*)d_in[0];
    const int* y = (const int*)d_in[1];
    const float* centers = (const float*)d_in[2];
    float* out = (float*)d_out;

    char* ws = (char*)d_ws;
    float* ce          = (float*)(ws);                 // 65,536 B
    float* d2          = (float*)(ws + 65536);         // 65,536 B
    float* s_part      = (float*)(ws + 131072);        // 16*1000*4 = 64,000 B
    float4* partials   = (float4*)(ws + 195072);       // 16,000 B
    float* new_centers = (float*)(ws + 211072);        // 4,000,000 B
    // everything read is written this launch -- no memset needed

    row_pass<<<NB / 4, 256, 0, stream>>>(x, y, centers, ce, d2);
    class_pass<<<NC, 256, 0, stream>>>(x, y, centers, ce, d2,
                                       new_centers, partials);
    dim3 cgrid(4, 16);
    col_partial<<<cgrid, 256, 0, stream>>>(new_centers, s_part);
    finalize<<<1, 1024, 0, stream>>>(s_part, partials, out);
}